// Round 2
// baseline (74.774 us; speedup 1.0000x reference)
//
#include <hip/hip_runtime.h>
#include <math.h>

// ROI adaptive max-pool to 7x7 (torch adaptive_max_pool2d bin semantics).
// feature_map: [B=2, C=256, H=50, W=50] fp32
// rois:        [R=192, 5] int32 (batch, x1, y1, x2, y2), 1<=w,h, x2<=W, y2<=H
// out:         [R, C, 7, 7] fp32
//
// Round 6 == Round 5 (broker timeout, no data; not stacking unverified
// changes). Theory under test: kernel is latency/issue-bound, not BW-bound.
//  - float2 lanes: wave = 2 channels x 32 col-pair lanes. One load instruction
//    covers a full row of TWO channels (was: one load per channel-row).
//    x0 = x1 & ~1 keeps every lane fully inside its row (W=50 even), so the
//    only OOB hazard is the absolute buffer end -> one clamp, no masks.
//  - overlap-row carry: adaptive bins overlap by <=1 row; carry the last
//    loaded row in a register so every ROI row is loaded EXACTLY once
//    (was h+6 .. 7h loads per channel, now h).
//  - CPB 16->8: LDS 29.1 KB -> 14.8 KB -> 8 blocks/CU = 32 waves/CU (full
//    occupancy, was 20). Grid = 192*32 = 6144.

#define OUT_N 7
#define WPB 4                 // waves per block
#define CHW 2                 // channels per wave (float2 col-pair lanes)
#define CPB (WPB * CHW)       // 8 channels per block
#define LDSW 66               // 64 cols + 2 pad (keeps ch stride % 32 != 0)

__global__ __launch_bounds__(256, 8) void roicrop_kernel(
    const float* __restrict__ fm,
    const int* __restrict__ rois,
    float* __restrict__ out,
    int R, int C, int H, int W, int nfm)
{
    __shared__ float tw[CPB][OUT_N][LDSW];   // 14.8 KB

    const int lane = threadIdx.x & 63;
    const int wave = threadIdx.x >> 6;        // 0..3
    const int cg_per_r = C / CPB;             // 32
    const int r  = blockIdx.x / cg_per_r;
    const int cg = blockIdx.x - r * cg_per_r;

    const int csub = lane >> 5;               // channel within wave: 0..1
    const int l2   = lane & 31;               // float2 lane within channel
    const int c    = cg * CPB + wave * CHW + csub;
    const int wc   = wave * CHW + csub;       // channel-in-block

    const int* roi = rois + r * 5;
    const int b  = roi[0];
    const int x1 = roi[1];
    const int y1 = roi[2];
    const int x2 = roi[3];
    const int y2 = roi[4];
    const int h = y2 - y1;
    const int w = x2 - x1;

    // Lane covers absolute columns [x0+2*l2, x0+2*l2+1]. Since x0 and W are
    // even, a lane is either fully inside its row (cols <= 49) or fully past
    // it; past-row lanes produce values the epilogue never reads. Clamp the
    // flat index so the last plane's trailing lanes stay inside the buffer.
    const int x0 = x1 & ~1;
    const unsigned colb = (unsigned)(x0 + 2 * l2);
    const unsigned base = (unsigned)(b * C + c) * (unsigned)(H * W) + colb;
    const unsigned lim  = (unsigned)(nfm - 2);

    float2 vprev = make_float2(-INFINITY, -INFINITY);  // last loaded row
    int prev_ye = y1;

    #pragma unroll
    for (int i = 0; i < OUT_N; ++i) {
        const int ys = y1 + (i * h) / OUT_N;
        const int ye = y1 + ((i + 1) * h + OUT_N - 1) / OUT_N;

        // Bins overlap by at most one row (ceil-floor); that row is exactly
        // the previous bin's last row, already in vprev.
        const bool carry = (ys < prev_ye);
        float2 m = carry ? vprev : make_float2(-INFINITY, -INFINITY);
        int y = carry ? prev_ye : ys;

        unsigned ia = base + (unsigned)(y * W);
        int rows = ye - y;

        while (rows >= 2) {                   // 2 independent loads in flight
            unsigned i0 = ia;                 if (i0 > lim) i0 = lim;
            unsigned i1 = ia + (unsigned)W;   if (i1 > lim) i1 = lim;
            const float2 v0 = *reinterpret_cast<const float2*>(fm + i0);
            const float2 v1 = *reinterpret_cast<const float2*>(fm + i1);
            m.x = fmaxf(m.x, fmaxf(v0.x, v1.x));
            m.y = fmaxf(m.y, fmaxf(v0.y, v1.y));
            vprev = v1;
            ia += (unsigned)(2 * W);
            rows -= 2;
        }
        if (rows) {
            unsigned i0 = ia;                 if (i0 > lim) i0 = lim;
            const float2 v0 = *reinterpret_cast<const float2*>(fm + i0);
            m.x = fmaxf(m.x, v0.x);
            m.y = fmaxf(m.y, v0.y);
            vprev = v0;
        }
        prev_ye = ye;

        *reinterpret_cast<float2*>(&tw[wc][i][2 * l2]) = m;  // ds_write_b64
    }
    __syncthreads();

    // Epilogue: CPB*49 = 392 outputs, 256 threads -> 2 rounds. Column bins
    // reduce from LDS (x0-based indexing, shifted by off = x1-x0).
    const int off = x1 - x0;
    float* obase = out + ((size_t)r * C + cg * CPB) * (OUT_N * OUT_N);
    for (int o = threadIdx.x; o < CPB * OUT_N * OUT_N; o += 256) {
        const int twc = o / (OUT_N * OUT_N);
        const int l   = o - twc * (OUT_N * OUT_N);
        const int i   = l / OUT_N;
        const int j   = l - i * OUT_N;
        const int xs  = (j * w) / OUT_N;
        const int xe  = ((j + 1) * w + OUT_N - 1) / OUT_N;
        float m = -INFINITY;
        for (int dx = xs; dx < xe; ++dx) {
            m = fmaxf(m, tw[twc][i][off + dx]);
        }
        obase[o] = m;                          // fully coalesced: offset == o
    }
}

extern "C" void kernel_launch(void* const* d_in, const int* in_sizes, int n_in,
                              void* d_out, int out_size, void* d_ws, size_t ws_size,
                              hipStream_t stream)
{
    const float* fm = (const float*)d_in[0];
    const int* rois = (const int*)d_in[1];
    float* out      = (float*)d_out;

    const int R = in_sizes[1] / 5;                        // 192
    const int C = out_size / (R * OUT_N * OUT_N);         // 256
    const int H = 50;
    const int W = 50;
    const int nfm = in_sizes[0];                          // B*C*H*W elements

    const int grid = R * (C / CPB);                       // 6144
    roicrop_kernel<<<grid, 256, 0, stream>>>(fm, rois, out, R, C, H, W, nfm);
}